// Round 1
// 533.651 us; speedup vs baseline: 1.0025x; 1.0025x over previous
//
#include <hip/hip_runtime.h>

// GRU (B=4096, T=2048, H=8, I=4) + fused FC (O=4), fp32.
// R3: 16 lanes per batch element (was 8) -> 1024 waves (was 512), covering all
// 1024 SIMDs (256 CU x 4 SIMD). The kernel was latency-bound (VALUBusy 35%,
// occupancy 5.9%, HBM 7%): one wave per SIMD, half the SIMDs idle, ~65% of
// each timestep exposed dependency stall. Each hidden unit's gate dot products
// are now split across a lane PAIR:
//   low half (g=0): x[0:2] part + h over quad(m),   + all biases
//   high half (g=1): x[2:4] part + h over quad(m^4)
// combined with one row_ror:8 DPP + add per accumulator. This halves per-wave
// issue work and doubles TLP; the recurrence critical path is unchanged.
//
// Lane layout within an element (q = lane&15, g = q>>3, m = q&7):
//  - pair (m, 8+m) both compute gates for hidden i = m (stay bit-identical)
//  - register `hold` carries h[own], own = g ? m^4 : m, so each quad of 4
//    lanes collectively holds a distinct half of h; quad_perm DPPs
//    (xor1/xor2/xor3, independent, not chained) gather it. Weights are
//    loaded pre-permuted to match (wh[d] pairs with h[own^d]).
//  - after h_new: high lanes refresh hold with hn from lane^4 via
//    xor7 (row_half_mirror) then xor3 (quad_perm) + cndmask.
// FC is pair-split the same way; results are banked 4 steps and stored as
// one 16-dword coalesced chunk per element (offset works out to exactly +q).

#define GRU_T 2048
#define GRU_H 8
#define GRU_I 4
#define GRU_O 4
#define PFD   8        // x prefetch depth (timesteps); T % PFD == 0

#define DPP_XOR1 0xB1   // quad_perm [1,0,3,2]
#define DPP_XOR2 0x4E   // quad_perm [2,3,0,1]
#define DPP_XOR3 0x1B   // quad_perm [3,2,1,0]
#define DPP_XOR7 0x141  // row_half_mirror (xor7 within aligned 8-lane halves)
#define DPP_ROR8 0x128  // row_ror:8 (== xor8 within a 16-lane row)

template <int CTRL>
__device__ __forceinline__ float dpp_movf(float v) {
    return __int_as_float(
        __builtin_amdgcn_mov_dpp(__float_as_int(v), CTRL, 0xf, 0xf, true));
}

__device__ __forceinline__ float fast_rcp(float x)  { return __builtin_amdgcn_rcpf(x); }
__device__ __forceinline__ float fast_exp2(float x) { return __builtin_amdgcn_exp2f(x); }

__device__ __forceinline__ float sigmoid_fast(float v) {
    return fast_rcp(1.0f + fast_exp2(-1.4426950408889634f * v));
}
__device__ __forceinline__ float tanh_fast(float v) {
    return 1.0f - 2.0f * fast_rcp(1.0f + fast_exp2(2.8853900817779268f * v));
}

__global__ __launch_bounds__(64, 1) void gru_fc_kernel(
    const float* __restrict__ x,
    const float* __restrict__ W_ih,
    const float* __restrict__ W_hh,
    const float* __restrict__ b_ih,
    const float* __restrict__ b_hh,
    const float* __restrict__ W_fc,
    const float* __restrict__ b_fc,
    float* __restrict__ out)
{
    constexpr int T = GRU_T;

    const int tid = blockIdx.x * 64 + (int)threadIdx.x;
    const int b   = tid >> 4;            // batch element
    const int q   = tid & 15;            // lane within element
    const int g   = (q >> 3) & 1;        // which half of the split this lane sums
    const int m   = q & 7;               // hidden index this lane pair computes
    const int own = g ? (m ^ 4) : m;     // hidden index held in `hold`/gath0

    // ---- weights into registers, pre-permuted per lane ----
    float wh_r[4], wh_z[4], wh_n[4], wf[4];
#pragma unroll
    for (int d = 0; d < 4; ++d) {
        const int k = own ^ d;           // partner of gath[d]
        wh_r[d] = W_hh[(0 * GRU_H + m) * GRU_H + k];
        wh_z[d] = W_hh[(1 * GRU_H + m) * GRU_H + k];
        wh_n[d] = W_hh[(2 * GRU_H + m) * GRU_H + k];
        wf[d]   = W_fc[(q & 3) * GRU_H + k];
    }
    float wi_r[2], wi_z[2], wi_n[2];
#pragma unroll
    for (int j = 0; j < 2; ++j) {
        const int k = 2 * g + j;         // g0: x[0],x[1]; g1: x[2],x[3]
        wi_r[j] = W_ih[(0 * GRU_H + m) * GRU_I + k];
        wi_z[j] = W_ih[(1 * GRU_H + m) * GRU_I + k];
        wi_n[j] = W_ih[(2 * GRU_H + m) * GRU_I + k];
    }
    // biases folded into the g0 partial only (added once per pair)
    const float br  = g ? 0.0f : (b_ih[m]            + b_hh[m]);
    const float bz  = g ? 0.0f : (b_ih[GRU_H + m]    + b_hh[GRU_H + m]);
    const float bxn = g ? 0.0f : b_ih[2 * GRU_H + m];
    const float bhn = g ? 0.0f : b_hh[2 * GRU_H + m];
    const float bo  = g ? 0.0f : b_fc[q & 3];

    // ---- loop-carried state ----
    float gath0 = 0.0f, gath1 = 0.0f, gath2 = 0.0f, gath3 = 0.0f; // h[own^d]
    float hprev = 0.0f;                                           // h[m]

    const float2* __restrict__ xp =
        reinterpret_cast<const float2*>(x) + ((size_t)b * T * 2 + g);
    float* __restrict__ op = out + (size_t)b * T * GRU_O + q;

    // ---- PFD-deep double-buffered register prefetch of x (float2/lane) ----
    float2 buf[PFD];
#pragma unroll
    for (int j = 0; j < PFD; ++j) buf[j] = xp[2 * j];

    float bank0 = 0.0f, bank1 = 0.0f, bank2 = 0.0f;

    for (int tb = 0; tb < T; tb += PFD) {
        const int tn = (tb + PFD) & (T - 1);   // wrap at end (values unused)
        float2 nxt[PFD];
#pragma unroll
        for (int j = 0; j < PFD; ++j) nxt[j] = xp[2 * (tn + j)];

#pragma unroll
        for (int j = 0; j < PFD; ++j) {
            const float2 xc = buf[j];

            float ar = br, az = bz, axn = bxn, ahn = bhn;
            ar  = fmaf(wi_r[0], xc.x, ar);   ar  = fmaf(wi_r[1], xc.y, ar);
            az  = fmaf(wi_z[0], xc.x, az);   az  = fmaf(wi_z[1], xc.y, az);
            axn = fmaf(wi_n[0], xc.x, axn);  axn = fmaf(wi_n[1], xc.y, axn);

            ar  = fmaf(wh_r[0], gath0, ar);  ar  = fmaf(wh_r[1], gath1, ar);
            ar  = fmaf(wh_r[2], gath2, ar);  ar  = fmaf(wh_r[3], gath3, ar);
            az  = fmaf(wh_z[0], gath0, az);  az  = fmaf(wh_z[1], gath1, az);
            az  = fmaf(wh_z[2], gath2, az);  az  = fmaf(wh_z[3], gath3, az);
            ahn = fmaf(wh_n[0], gath0, ahn); ahn = fmaf(wh_n[1], gath1, ahn);
            ahn = fmaf(wh_n[2], gath2, ahn); ahn = fmaf(wh_n[3], gath3, ahn);

            // pair-combine (xor8): both halves end with identical full sums
            ar  += dpp_movf<DPP_ROR8>(ar);
            az  += dpp_movf<DPP_ROR8>(az);
            ahn += dpp_movf<DPP_ROR8>(ahn);
            axn += dpp_movf<DPP_ROR8>(axn);

            const float r  = sigmoid_fast(ar);
            const float z  = sigmoid_fast(az);
            const float n  = tanh_fast(fmaf(r, ahn, axn));
            const float hn = fmaf(z, hprev - n, n);   // (1-z)*n + z*h
            hprev = hn;

            // hold refresh: high lanes need hn of lane^4 (xor7 then xor3)
            const float f1   = dpp_movf<DPP_XOR7>(hn);
            const float f2   = dpp_movf<DPP_XOR3>(f1);
            const float hold = (q & 8) ? f2 : hn;

            // quad gather of fresh h (independent DPPs; feeds FC now, gates next)
            gath0 = hold;
            gath1 = dpp_movf<DPP_XOR1>(hold);
            gath2 = dpp_movf<DPP_XOR2>(hold);
            gath3 = dpp_movf<DPP_XOR3>(hold);

            // fused FC, pair-split like the gates
            float fcp = bo;
            fcp = fmaf(wf[0], gath0, fcp);  fcp = fmaf(wf[1], gath1, fcp);
            fcp = fmaf(wf[2], gath2, fcp);  fcp = fmaf(wf[3], gath3, fcp);
            const float fc = fcp + dpp_movf<DPP_ROR8>(fcp);

            // bank 4 steps, then one coalesced 16-dword store per element:
            // lane q stores step (q>>2), output (q&3) -> flat offset +q
            if ((j & 3) == 0)      bank0 = fc;
            else if ((j & 3) == 1) bank1 = fc;
            else if ((j & 3) == 2) bank2 = fc;
            else {
                const float v01 = (q & 4) ? bank1 : bank0;
                const float v23 = (q & 4) ? fc    : bank2;
                const float val = (q & 8) ? v23   : v01;
                op[(size_t)(tb + j - 3) * GRU_O] = val;
            }
        }

#pragma unroll
        for (int j = 0; j < PFD; ++j) buf[j] = nxt[j];
    }
}

extern "C" void kernel_launch(void* const* d_in, const int* in_sizes, int n_in,
                              void* d_out, int out_size, void* d_ws, size_t ws_size,
                              hipStream_t stream) {
    const float* x    = (const float*)d_in[0];
    const float* W_ih = (const float*)d_in[1];
    const float* W_hh = (const float*)d_in[2];
    const float* b_ih = (const float*)d_in[3];
    const float* b_hh = (const float*)d_in[4];
    const float* W_fc = (const float*)d_in[5];
    const float* b_fc = (const float*)d_in[6];
    float* out = (float*)d_out;

    const int B = in_sizes[0] / (GRU_T * GRU_I);   // 4096
    dim3 grid((unsigned)(B * 16 / 64)), block(64); // 16 lanes/elem -> 1024 waves
    hipLaunchKernelGGL(gru_fc_kernel, grid, block, 0, stream,
                       x, W_ih, W_hh, b_ih, b_hh, W_fc, b_fc, out);
}

// Round 2
// 482.583 us; speedup vs baseline: 1.1086x; 1.1058x over previous
//
#include <hip/hip_runtime.h>

// GRU (B=4096, T=2048, H=8, I=4) + fused FC (O=4), fp32.
// R4: depth-first redesign. R2 (8 lanes/elem, ~70 inst/step) and R3 (16
// lanes/elem, ~58 inst/step, 2x occupancy) both measured ~435 cyc/step ->
// the kernel is bound by the serial dependency CHAIN of the recurrence
// (~22 dependent ops x ~20 cyc effective latency each), not issue/occupancy/
// memory. This version minimizes chain DEPTH (22 -> 13):
//  - 16 lanes/elem with both 8-lane halves fully DUPLICATED (no pair-split,
//    no hold-fixup chain). Element == one DPP row of 16, so row_ror:1..7
//    gather ALL 7 other h values at depth 1 (rotation order; weights are
//    loaded pre-permuted by (m-r)&7).
//  - r-gate dot as a 4-leaf fma TREE (ar ready at depth 5); z/n gates as two
//    4-chains (they have slack in the cycle).
//  - sigmoid/tanh exp2-scale constants folded into weights+biases (kills the
//    mul in front of each exp2).
//  - update rewritten as hn = fma(-2*omz, u, c1) with omz = 1-z =
//    rcp(1+exp2(az')), u = rcp(1+exp2(yn')), c1 = fma(omz, 1-h, h):
//    the tanh tail and the whole z-branch leave the critical cycle.
//    Cycle: rot@1, tree@5, exp@6 add@7 rcp@8, fma@9, exp@10 add@11 rcp@12,
//    hn=fma@13.
//  - FC computed LAGGED one step (on h(t-1)) so it reuses the same rotation
//    gather; epilogue flushes step T-1. Ping-pong x buffers (no copy movs).

#define GRU_T 2048
#define GRU_H 8
#define GRU_I 4
#define GRU_O 4
#define PFD   8        // per ping-pong half; 2*PFD must divide T

#define DPP_ROR(n) (0x120 + (n))   // row_ror:n : lane i <- lane (i-n)&15

template <int CTRL>
__device__ __forceinline__ float dpp_movf(float v) {
    return __int_as_float(
        __builtin_amdgcn_mov_dpp(__float_as_int(v), CTRL, 0xf, 0xf, true));
}

__device__ __forceinline__ float fast_rcp(float x)  { return __builtin_amdgcn_rcpf(x); }
__device__ __forceinline__ float fast_exp2(float x) { return __builtin_amdgcn_exp2f(x); }

__global__ __launch_bounds__(64, 1) void gru_fc_kernel(
    const float* __restrict__ x,
    const float* __restrict__ W_ih,
    const float* __restrict__ W_hh,
    const float* __restrict__ b_ih,
    const float* __restrict__ b_hh,
    const float* __restrict__ W_fc,
    const float* __restrict__ b_fc,
    float* __restrict__ out)
{
    const int tid = blockIdx.x * 64 + (int)threadIdx.x;
    const int b   = tid >> 4;            // batch element (4 per wave)
    const int q   = tid & 15;            // lane within element (one DPP row)
    const int m   = q & 7;               // hidden index this lane owns
    const int o   = q & 3;               // FC output index (4x duplicated)

    // scale folding: sigma(a) = rcp(1+exp2(SR*a)); 1-sigma(a) =
    // rcp(1+exp2(SZ*a)); tanh(y) = 1 - 2*rcp(1+exp2(SN*y))
    const float SR = -1.4426950408889634f;
    const float SZ =  1.4426950408889634f;
    const float SN =  2.8853900817779268f;

    float whr[8], whz[8], whn[8], wf[8];
#pragma unroll
    for (int r = 0; r < 8; ++r) {
        const int k = (m - r) & 7;       // rot[r] holds h[(m-r)&7]
        whr[r] = SR * W_hh[(0 * GRU_H + m) * GRU_H + k];
        whz[r] = SZ * W_hh[(1 * GRU_H + m) * GRU_H + k];
        whn[r] = SN * W_hh[(2 * GRU_H + m) * GRU_H + k];
        wf[r]  = W_fc[o * GRU_H + k];
    }
    float wir[4], wiz[4], win[4];
#pragma unroll
    for (int k = 0; k < 4; ++k) {
        wir[k] = SR * W_ih[(0 * GRU_H + m) * GRU_I + k];
        wiz[k] = SZ * W_ih[(1 * GRU_H + m) * GRU_I + k];
        win[k] = SN * W_ih[(2 * GRU_H + m) * GRU_I + k];
    }
    const float br  = SR * (b_ih[m] + b_hh[m]);
    const float bz  = SZ * (b_ih[GRU_H + m] + b_hh[GRU_H + m]);
    const float bxn = SN * b_ih[2 * GRU_H + m];
    const float bhn = SN * b_hh[2 * GRU_H + m];
    const float bo  = b_fc[o];

    float hprev = 0.0f;
    float bank0 = 0.0f, bank1 = 0.0f, bank2 = 0.0f;

    const float4* __restrict__ xp = reinterpret_cast<const float4*>(x) + (size_t)b * GRU_T;
    float* __restrict__ op = out + (size_t)b * GRU_T * GRU_O + q;

    float4 bufA[PFD], bufB[PFD];
#pragma unroll
    for (int j = 0; j < PFD; ++j) bufA[j] = xp[j];

#define GRU_STEP(XC, TCUR, JM)                                                 \
    do {                                                                       \
        const float4 xc = (XC);                                                \
        /* x-parts + helpers: independent of h, fill stall shadows */          \
        const float xrA = fmaf(wir[1], xc.y, fmaf(wir[0], xc.x, br));          \
        const float xrB = fmaf(wir[3], xc.w, wir[2] * xc.z);                   \
        const float xzA = fmaf(wiz[1], xc.y, fmaf(wiz[0], xc.x, bz));          \
        const float xzB = fmaf(wiz[3], xc.w, wiz[2] * xc.z);                   \
        const float xn_ = fmaf(win[3], xc.w, fmaf(win[2], xc.z,                \
                          fmaf(win[1], xc.y, fmaf(win[0], xc.x, bxn))));       \
        const float onemh = 1.0f - hprev;                                      \
        /* depth-1 rotation gather: rk = h_prev[(m-k)&7] */                    \
        const float r1 = dpp_movf<DPP_ROR(1)>(hprev);                          \
        const float r2 = dpp_movf<DPP_ROR(2)>(hprev);                          \
        const float r3 = dpp_movf<DPP_ROR(3)>(hprev);                          \
        const float r4 = dpp_movf<DPP_ROR(4)>(hprev);                          \
        const float r5 = dpp_movf<DPP_ROR(5)>(hprev);                          \
        const float r6 = dpp_movf<DPP_ROR(6)>(hprev);                          \
        const float r7 = dpp_movf<DPP_ROR(7)>(hprev);                          \
        /* r-gate: 4-leaf tree, ar ready at depth 5 (critical path) */         \
        const float tA = fmaf(whr[1], r1, fmaf(whr[0], hprev, xrA));           \
        const float tB = fmaf(whr[3], r3, fmaf(whr[2], r2, xrB));              \
        const float tC = fmaf(whr[5], r5, whr[4] * r4);                        \
        const float tD = fmaf(whr[7], r7, whr[6] * r6);                        \
        const float ar = (tA + tB) + (tC + tD);                                \
        /* z / n-h dots: two 4-chains (off-critical slack) */                  \
        const float zA = fmaf(whz[3], r3, fmaf(whz[2], r2,                     \
                         fmaf(whz[1], r1, fmaf(whz[0], hprev, xzA))));         \
        const float zB = fmaf(whz[7], r7, fmaf(whz[6], r6,                     \
                         fmaf(whz[5], r5, fmaf(whz[4], r4, xzB))));            \
        const float az = zA + zB;                                              \
        const float nA = fmaf(whn[3], r3, fmaf(whn[2], r2,                     \
                         fmaf(whn[1], r1, fmaf(whn[0], hprev, bhn))));         \
        const float nB = fmaf(whn[7], r7, fmaf(whn[6], r6,                     \
                         fmaf(whn[5], r5, whn[4] * r4)));                      \
        const float ahn = nA + nB;                                             \
        /* lagged FC on h(t-1), reusing the rotation gather */                 \
        const float fA = fmaf(wf[3], r3, fmaf(wf[2], r2,                       \
                         fmaf(wf[1], r1, fmaf(wf[0], hprev, bo))));            \
        const float fB = fmaf(wf[7], r7, fmaf(wf[6], r6,                       \
                         fmaf(wf[5], r5, wf[4] * r4)));                        \
        const float fc = fA + fB;                                              \
        /* nonlinear tail (cycle: exp add rcp, fma, exp add rcp, fma) */       \
        const float rg  = fast_rcp(1.0f + fast_exp2(ar));                      \
        const float omz = fast_rcp(1.0f + fast_exp2(az));     /* = 1-z */      \
        const float c1  = fmaf(omz, onemh, hprev);                             \
        const float m2z = -2.0f * omz;                                         \
        const float yn  = fmaf(rg, ahn, xn_);                                  \
        const float u   = fast_rcp(1.0f + fast_exp2(yn));                      \
        hprev = fmaf(m2z, u, c1);        /* h + omz*(1-h) - 2*omz*u */         \
        /* bank fc by s=(t-1)&3; store 4 steps per 16-dword chunk */           \
        if (((JM) & 3) == 1)      bank0 = fc;                                  \
        else if (((JM) & 3) == 2) bank1 = fc;                                  \
        else if (((JM) & 3) == 3) bank2 = fc;                                  \
        else if ((TCUR) != 0) {                                                \
            const float v01 = (q & 4) ? bank1 : bank0;                         \
            const float v23 = (q & 4) ? fc    : bank2;                         \
            const float val = (q & 8) ? v23   : v01;                           \
            op[(size_t)((TCUR) - 4) * GRU_O] = val;                            \
        }                                                                      \
    } while (0)

    for (int tb = 0; tb < GRU_T; tb += 2 * PFD) {
#pragma unroll
        for (int j = 0; j < PFD; ++j) bufB[j] = xp[tb + PFD + j];
#pragma unroll
        for (int j = 0; j < PFD; ++j) GRU_STEP(bufA[j], tb + j, j);
        const int tn = (tb + 2 * PFD) & (GRU_T - 1);   // wrap; values unused
#pragma unroll
        for (int j = 0; j < PFD; ++j) bufA[j] = xp[tn + j];
#pragma unroll
        for (int j = 0; j < PFD; ++j) GRU_STEP(bufB[j], tb + PFD + j, j);
    }

    // epilogue: flush lagged FC for step T-1 (h = final hprev)
    {
        const float r1 = dpp_movf<DPP_ROR(1)>(hprev);
        const float r2 = dpp_movf<DPP_ROR(2)>(hprev);
        const float r3 = dpp_movf<DPP_ROR(3)>(hprev);
        const float r4 = dpp_movf<DPP_ROR(4)>(hprev);
        const float r5 = dpp_movf<DPP_ROR(5)>(hprev);
        const float r6 = dpp_movf<DPP_ROR(6)>(hprev);
        const float r7 = dpp_movf<DPP_ROR(7)>(hprev);
        const float fA = fmaf(wf[3], r3, fmaf(wf[2], r2,
                         fmaf(wf[1], r1, fmaf(wf[0], hprev, bo))));
        const float fB = fmaf(wf[7], r7, fmaf(wf[6], r6,
                         fmaf(wf[5], r5, wf[4] * r4)));
        const float fc = fA + fB;
        const float v01 = (q & 4) ? bank1 : bank0;
        const float v23 = (q & 4) ? fc    : bank2;
        const float val = (q & 8) ? v23   : v01;
        op[(size_t)(GRU_T - 4) * GRU_O] = val;
    }
#undef GRU_STEP
}

extern "C" void kernel_launch(void* const* d_in, const int* in_sizes, int n_in,
                              void* d_out, int out_size, void* d_ws, size_t ws_size,
                              hipStream_t stream) {
    const float* x    = (const float*)d_in[0];
    const float* W_ih = (const float*)d_in[1];
    const float* W_hh = (const float*)d_in[2];
    const float* b_ih = (const float*)d_in[3];
    const float* b_hh = (const float*)d_in[4];
    const float* W_fc = (const float*)d_in[5];
    const float* b_fc = (const float*)d_in[6];
    float* out = (float*)d_out;

    const int B = in_sizes[0] / (GRU_T * GRU_I);   // 4096
    dim3 grid((unsigned)(B * 16 / 64)), block(64); // 16 lanes/elem, 1024 waves
    hipLaunchKernelGGL(gru_fc_kernel, grid, block, 0, stream,
                       x, W_ih, W_hh, b_ih, b_hh, W_fc, b_fc, out);
}